// Round 20
// baseline (140.441 us; speedup 1.0000x reference)
//
#include <hip/hip_runtime.h>

#define N_NODES 16384
#define N_EDGES 262144
#define D 256
#define B_GRAPHS 32
#define NODES_PER_GRAPH 512   // N_NODES / B_GRAPHS
#define MAXDEG 64             // Poisson(16): P(deg>64) ~ 1e-17

// ---------------------------------------------------------------------------
// 32x32-tile f32 GEMM helper: acc[4] += (A@B) tile at (r0,c0).
// BOTH panels staged to LDS via float4 (1 coalesced load-round per 32-k step,
// 8 rounds total vs R19's 32 scalar-B rounds). Bs reads conflict-free
// (c = t&31 consecutive); As reads broadcast (same row across half-wave).
// ---------------------------------------------------------------------------
struct MMLds { float As[32][33]; float Bs[32][33]; };

__device__ __forceinline__ void mm32(const float* __restrict__ A,
                                     const float* __restrict__ B,
                                     int r0, int c0, MMLds& L, float acc[4]) {
    const int t  = threadIdx.x;
    const int lr = t >> 3, lc4 = t & 7;     // stage coords: 32 rows x 8 float4
    const int rq = t >> 5, c = t & 31;      // compute: rows rq*4+q, col c
    for (int k0 = 0; k0 < D; k0 += 32) {
        __syncthreads();
        *(float4*)&L.As[lr][lc4 * 4] =
            *(const float4*)&A[(size_t)(r0 + lr) * D + k0 + lc4 * 4];
        *(float4*)&L.Bs[lr][lc4 * 4] =
            *(const float4*)&B[(size_t)(k0 + lr) * D + c0 + lc4 * 4];
        __syncthreads();
        #pragma unroll
        for (int kk = 0; kk < 32; ++kk) {
            float bv = L.Bs[kk][c];
            acc[0] += L.As[rq * 4 + 0][kk] * bv;
            acc[1] += L.As[rq * 4 + 1][kk] * bv;
            acc[2] += L.As[rq * 4 + 2][kk] * bv;
            acc[3] += L.As[rq * 4 + 3][kk] * bv;
        }
    }
}

__device__ __forceinline__ void mm32_store(float* __restrict__ O, int r0, int c0,
                                           const float acc[4]) {
    const int rq = threadIdx.x >> 5, c = threadIdx.x & 31;
    #pragma unroll
    for (int q = 0; q < 4; ++q)
        O[(size_t)(r0 + rq * 4 + q) * D + c0 + c] = acc[q];
}

// ---------------------------------------------------------------------------
// Dispatch 1: bid<64 zero cnt; bid in [64,256) P tiles; bid==256 bias2.
//   P2=Wl2@Wl3 ; P1=Wr2@Wl3+Wl2@Wr3 ; P0=Wr2@Wr3 ; bias2=b2@(Wl3+Wr3)+b3
// (P depends only on weights — rides the first dispatch's idle capacity.)
// ---------------------------------------------------------------------------
__global__ __launch_bounds__(256) void init_p_kernel(
    int* __restrict__ cnt,
    const float* __restrict__ Wl, const float* __restrict__ Wr,
    const float* __restrict__ bl,
    float* __restrict__ P2, float* __restrict__ P1, float* __restrict__ P0,
    float* __restrict__ bias2)
{
    __shared__ MMLds L;
    const int bid = blockIdx.x;
    const int t = threadIdx.x;
    if (bid < 64) { cnt[bid * 256 + t] = 0; return; }
    if (bid == 256) {
        const float* b2 = bl + D;
        const float* b3 = bl + 2 * D;
        const float* L3 = Wl + (size_t)2 * D * D;
        const float* R3 = Wr + (size_t)2 * D * D;
        float s = 0.f;
        #pragma unroll 8
        for (int k = 0; k < D; ++k)
            s += b2[k] * (L3[(size_t)k * D + t] + R3[(size_t)k * D + t]);
        bias2[t] = s + b3[t];
        return;
    }
    int pb = bid - 64;                   // 0..191
    int mat = pb / 64, tile = pb % 64;
    int r0 = (tile >> 3) * 32, c0 = (tile & 7) * 32;
    const float* L2 = Wl + (size_t)1 * D * D;
    const float* R2 = Wr + (size_t)1 * D * D;
    const float* L3 = Wl + (size_t)2 * D * D;
    const float* R3 = Wr + (size_t)2 * D * D;
    float acc[4] = {0.f, 0.f, 0.f, 0.f};
    if (mat == 0) {
        mm32(L2, L3, r0, c0, L, acc);
        mm32_store(P2, r0, c0, acc);
    } else if (mat == 1) {
        mm32(R2, L3, r0, c0, L, acc);
        mm32(L2, R3, r0, c0, L, acc);
        mm32_store(P1, r0, c0, acc);
    } else {
        mm32(R2, R3, r0, c0, L, acc);
        mm32_store(P0, r0, c0, acc);
    }
}

// ---------------------------------------------------------------------------
// Dispatch 2: bid<1024 bucket fill; bid in [1024,1280) Q tiles; bid==1280 beff.
//   Q3=Wl1@P2 ; Q2=Wr1@P2+Wl1@P1 ; Q1=Wr1@P1+Wl1@P0 ; Q0=Wr1@P0
//   beff = b1@(P2+P1+P0) + bias2        (P/bias2 from dispatch 1)
// ---------------------------------------------------------------------------
__global__ __launch_bounds__(256) void fill_q_kernel(
    const int* __restrict__ edge, int* __restrict__ cnt, int* __restrict__ col,
    const float* __restrict__ Wl, const float* __restrict__ Wr,
    const float* __restrict__ bl,
    const float* __restrict__ P2, const float* __restrict__ P1,
    const float* __restrict__ P0, const float* __restrict__ bias2,
    float* __restrict__ Q, float* __restrict__ beff)
{
    __shared__ MMLds L;
    const int bid = blockIdx.x;
    const int t = threadIdx.x;
    if (bid < 1024) {
        int e = bid * 256 + t;
        int dst = edge[N_EDGES + e];
        int src = edge[e];
        int slot = atomicAdd(&cnt[dst], 1);
        if (slot < MAXDEG) col[dst * MAXDEG + slot] = src;
        return;
    }
    if (bid == 1280) {
        const float* b1 = bl;
        float s = 0.f;
        #pragma unroll 8
        for (int k = 0; k < D; ++k)
            s += b1[k] * (P2[(size_t)k * D + t] + P1[(size_t)k * D + t]
                        + P0[(size_t)k * D + t]);
        beff[t] = s + bias2[t];
        return;
    }
    int qb = bid - 1024;                 // 0..255
    int mat = qb >> 6, tile = qb & 63;
    int r0 = (tile >> 3) * 32, c0 = (tile & 7) * 32;
    const float* L1 = Wl;
    const float* R1 = Wr;
    float acc[4] = {0.f, 0.f, 0.f, 0.f};
    if (mat == 0) {
        mm32(L1, P2, r0, c0, L, acc);
        mm32_store(Q + 3 * (size_t)D * D, r0, c0, acc);
    } else if (mat == 1) {
        mm32(R1, P2, r0, c0, L, acc);
        mm32(L1, P1, r0, c0, L, acc);
        mm32_store(Q + 2 * (size_t)D * D, r0, c0, acc);
    } else if (mat == 2) {
        mm32(R1, P1, r0, c0, L, acc);
        mm32(L1, P0, r0, c0, L, acc);
        mm32_store(Q + 1 * (size_t)D * D, r0, c0, acc);
    } else {
        mm32(R1, P0, r0, c0, L, acc);
        mm32_store(Q + 0 * (size_t)D * D, r0, c0, acc);
    }
}

// ---------------------------------------------------------------------------
// Dispatch 3: aggx pure (R14-proven): A[i] = mean_{j in in(i)} x[j]
// ---------------------------------------------------------------------------
__global__ __launch_bounds__(256) void aggx_kernel(const float* __restrict__ x,
                                                   const int* __restrict__ cnt,
                                                   const int* __restrict__ col,
                                                   float* __restrict__ A) {
    int node = blockIdx.x * 4 + (threadIdx.x >> 6);
    int lane = threadIdx.x & 63;
    int c = cnt[node];
    if (c > MAXDEG) c = MAXDEG;
    int my = (lane < c) ? col[node * MAXDEG + lane] : 0;
    float a0 = 0.f, a1 = 0.f, a2 = 0.f, a3 = 0.f;
    int j = 0;
    for (; j + 8 <= c; j += 8) {
        float4 v[8];
        #pragma unroll
        for (int q = 0; q < 8; ++q) {
            int s = __shfl(my, j + q);
            v[q] = *(const float4*)&x[(size_t)s * D + lane * 4];
        }
        #pragma unroll
        for (int q = 0; q < 8; ++q) {
            a0 += v[q].x; a1 += v[q].y; a2 += v[q].z; a3 += v[q].w;
        }
    }
    for (; j < c; ++j) {
        int s = __shfl(my, j);
        float4 v = *(const float4*)&x[(size_t)s * D + lane * 4];
        a0 += v.x; a1 += v.y; a2 += v.z; a3 += v.w;
    }
    float id = 1.0f / (float)(c < 1 ? 1 : c);
    float4 r = make_float4(a0 * id, a1 * id, a2 * id, a3 * id);
    *(float4*)&A[(size_t)node * D + lane * 4] = r;
}

// ---------------------------------------------------------------------------
// Dispatch 4: telescoped tail (R19-verbatim, hardware-validated):
//   g0=x[r], g1=A[r], g2=mean_{n in(r)} A[n], g3=mean_n mean_{m in(n)} A[m]
//   X3[r] = g3@Q3 + g2@Q2 + g1@Q1 + g0@Q0 + beff ; out = MLP head(X3)
// ---------------------------------------------------------------------------
__global__ __launch_bounds__(1024) void tail_kernel(
    const int* __restrict__ cnt, const int* __restrict__ col,
    const float* __restrict__ x, const float* __restrict__ A,
    const float* __restrict__ Q, const float* __restrict__ beff,
    const float* __restrict__ Wh, const float* __restrict__ bh,
    const float* __restrict__ Wo, const float* __restrict__ bo,
    float* __restrict__ out)
{
    __shared__ float g0[D], g1[D], g2[D], g3[D];
    __shared__ float v0[D];
    __shared__ float part1[16][D];
    __shared__ float part2[16][D];
    __shared__ int nbr[MAXDEG];
    __shared__ int snr;

    const int b = blockIdx.x, t = threadIdx.x;
    const int w = t >> 6, lane = t & 63;
    const int root = b * NODES_PER_GRAPH;

    if (t == 0) { int cc = cnt[root]; snr = (cc > MAXDEG) ? MAXDEG : cc; }
    __syncthreads();
    const int c0 = snr;
    if (t < c0) nbr[t] = col[root * MAXDEG + t];
    if (t < D) {
        g0[t] = x[(size_t)root * D + t];
        g1[t] = A[(size_t)root * D + t];
    }
    __syncthreads();

    // ---- 1/2-hop gathers of A (R14-proven) ----
    {
        float p1[4] = {0.f, 0.f, 0.f, 0.f}, p2[4] = {0.f, 0.f, 0.f, 0.f};
        for (int i = w; i < c0; i += 16) {
            int n = nbr[i];
            {
                float4 v = *(const float4*)&A[(size_t)n * D + lane * 4];
                p1[0] += v.x; p1[1] += v.y; p1[2] += v.z; p1[3] += v.w;
            }
            int c = cnt[n]; if (c > MAXDEG) c = MAXDEG;
            int my = (lane < c) ? col[n * MAXDEG + lane] : 0;
            float a[4] = {0.f, 0.f, 0.f, 0.f};
            int j = 0;
            for (; j + 8 <= c; j += 8) {
                float4 v[8];
                #pragma unroll
                for (int q = 0; q < 8; ++q) {
                    int s = __shfl(my, j + q);
                    v[q] = *(const float4*)&A[(size_t)s * D + lane * 4];
                }
                #pragma unroll
                for (int q = 0; q < 8; ++q) {
                    a[0] += v[q].x; a[1] += v[q].y; a[2] += v[q].z; a[3] += v[q].w;
                }
            }
            for (; j < c; ++j) {
                int s = __shfl(my, j);
                float4 v = *(const float4*)&A[(size_t)s * D + lane * 4];
                a[0] += v.x; a[1] += v.y; a[2] += v.z; a[3] += v.w;
            }
            float id = 1.0f / (float)(c < 1 ? 1 : c);
            #pragma unroll
            for (int q = 0; q < 4; ++q) p2[q] += a[q] * id;
        }
        #pragma unroll
        for (int q = 0; q < 4; ++q) {
            part1[w][lane * 4 + q] = p1[q];
            part2[w][lane * 4 + q] = p2[q];
        }
        __syncthreads();
        if (t < D) {
            float s1 = 0.f, s2 = 0.f;
            #pragma unroll
            for (int ww = 0; ww < 16; ++ww) { s1 += part1[ww][t]; s2 += part2[ww][t]; }
            float id0 = 1.0f / (float)(c0 < 1 ? 1 : c0);
            g2[t] = s1 * id0;
            g3[t] = s2 * id0;
        }
        __syncthreads();
    }

    const int c = t & 255, kq = t >> 8;
    // ---- single folded phase: X3 = g3@Q3 + g2@Q2 + g1@Q1 + g0@Q0 + beff ----
    {
        const float* Q0 = Q;
        const float* Q1 = Q + (size_t)D * D;
        const float* Q2 = Q + 2 * (size_t)D * D;
        const float* Q3 = Q + 3 * (size_t)D * D;
        float a = 0.f;
        #pragma unroll 8
        for (int k0 = 0; k0 < 64; ++k0) {
            int k = kq * 64 + k0;
            a += g0[k] * Q0[(size_t)k * D + c] + g1[k] * Q1[(size_t)k * D + c]
               + g2[k] * Q2[(size_t)k * D + c] + g3[k] * Q3[(size_t)k * D + c];
        }
        part1[kq][c] = a;
        __syncthreads();
        if (t < D) {
            float s = part1[0][t] + part1[1][t] + part1[2][t] + part1[3][t];
            v0[t] = s + beff[t];
        }
        __syncthreads();
    }
    // ---- MLP head (R14-proven) ----
    for (int l = 0; l < 3; ++l) {
        const float* W = (l < 2) ? Wh + (size_t)l * D * D : Wo;
        float a = 0.f;
        #pragma unroll
        for (int k0 = 0; k0 < 64; k0 += 8) {
            float wv[8];
            #pragma unroll
            for (int j = 0; j < 8; ++j)
                wv[j] = W[(size_t)(kq * 64 + k0 + j) * D + c];
            #pragma unroll
            for (int j = 0; j < 8; ++j)
                a += v0[kq * 64 + k0 + j] * wv[j];
        }
        part1[kq][c] = a;
        __syncthreads();
        if (t < D) {
            float v = part1[0][t] + part1[1][t] + part1[2][t] + part1[3][t]
                    + ((l < 2) ? bh[(size_t)l * D + t] : bo[t]);
            if (l < 2) v0[t] = fmaxf(v, 0.f);
            else       out[(size_t)b * D + t] = v;
        }
        __syncthreads();
    }
}

// ---------------------------------------------------------------------------
extern "C" void kernel_launch(void* const* d_in, const int* in_sizes, int n_in,
                              void* d_out, int out_size, void* d_ws, size_t ws_size,
                              hipStream_t stream) {
    const float* x    = (const float*)d_in[0];
    const int*   edge = (const int*)d_in[1];
    const float* Wl   = (const float*)d_in[2];
    const float* bl   = (const float*)d_in[3];
    const float* Wr   = (const float*)d_in[4];
    const float* Wh   = (const float*)d_in[5];
    const float* bh   = (const float*)d_in[6];
    const float* Wo   = (const float*)d_in[7];
    const float* bo   = (const float*)d_in[8];
    float* out = (float*)d_out;

    char* w = (char*)d_ws;
    auto alloc = [&](size_t bytes) {
        char* p = w;
        w += (bytes + 255) & ~(size_t)255;
        return p;
    };
    int*   cnt   = (int*)  alloc((size_t)N_NODES * 4);
    int*   col   = (int*)  alloc((size_t)N_NODES * MAXDEG * 4);
    float* A     = (float*)alloc((size_t)N_NODES * D * 4);
    float* P2    = (float*)alloc((size_t)D * D * 4);
    float* P1    = (float*)alloc((size_t)D * D * 4);
    float* P0    = (float*)alloc((size_t)D * D * 4);
    float* bias2 = (float*)alloc((size_t)D * 4);
    float* Q     = (float*)alloc((size_t)4 * D * D * 4);
    float* beff  = (float*)alloc((size_t)D * 4);

    init_p_kernel<<<257, 256, 0, stream>>>(cnt, Wl, Wr, bl, P2, P1, P0, bias2);
    fill_q_kernel<<<1281, 256, 0, stream>>>(edge, cnt, col, Wl, Wr, bl,
                                            P2, P1, P0, bias2, Q, beff);
    aggx_kernel<<<N_NODES / 4, 256, 0, stream>>>(x, cnt, col, A);
    tail_kernel<<<B_GRAPHS, 1024, 0, stream>>>(cnt, col, x, A, Q, beff,
                                               Wh, bh, Wo, bo, out);
}

// Round 21
// 112.034 us; speedup vs baseline: 1.2536x; 1.2536x over previous
//
#include <hip/hip_runtime.h>

#define N_NODES 16384
#define N_EDGES 262144
#define D 256
#define B_GRAPHS 32
#define NODES_PER_GRAPH 512   // N_NODES / B_GRAPHS
#define MAXDEG 64             // Poisson(16): P(deg>64) ~ 1e-17

// ---------------------------------------------------------------------------
// 32x32-tile f32 GEMM helper (R20's mm32 — measured harmless in dispatch 1):
// both panels staged to LDS via float4; Bs reads conflict-free, As broadcast.
// ---------------------------------------------------------------------------
struct MMLds { float As[32][33]; float Bs[32][33]; };

__device__ __forceinline__ void mm32(const float* __restrict__ A,
                                     const float* __restrict__ B,
                                     int r0, int c0, MMLds& L, float acc[4]) {
    const int t  = threadIdx.x;
    const int lr = t >> 3, lc4 = t & 7;
    const int rq = t >> 5, c = t & 31;
    for (int k0 = 0; k0 < D; k0 += 32) {
        __syncthreads();
        *(float4*)&L.As[lr][lc4 * 4] =
            *(const float4*)&A[(size_t)(r0 + lr) * D + k0 + lc4 * 4];
        *(float4*)&L.Bs[lr][lc4 * 4] =
            *(const float4*)&B[(size_t)(k0 + lr) * D + c0 + lc4 * 4];
        __syncthreads();
        #pragma unroll
        for (int kk = 0; kk < 32; ++kk) {
            float bv = L.Bs[kk][c];
            acc[0] += L.As[rq * 4 + 0][kk] * bv;
            acc[1] += L.As[rq * 4 + 1][kk] * bv;
            acc[2] += L.As[rq * 4 + 2][kk] * bv;
            acc[3] += L.As[rq * 4 + 3][kk] * bv;
        }
    }
}

__device__ __forceinline__ void mm32_store(float* __restrict__ O, int r0, int c0,
                                           const float acc[4]) {
    const int rq = threadIdx.x >> 5, c = threadIdx.x & 31;
    #pragma unroll
    for (int q = 0; q < 4; ++q)
        O[(size_t)(r0 + rq * 4 + q) * D + c0 + c] = acc[q];
}

// ---------------------------------------------------------------------------
// Dispatch 1: bid<64 zero cnt; bid in [64,256) P tiles; bid==256 bias2.
//   P2=Wl2@Wl3 ; P1=Wr2@Wl3+Wl2@Wr3 ; P0=Wr2@Wr3 ; bias2=b2@(Wl3+Wr3)+b3
// (R20 measured this placement as harmless — init_p never in top-5.)
// ---------------------------------------------------------------------------
__global__ __launch_bounds__(256) void init_p_kernel(
    int* __restrict__ cnt,
    const float* __restrict__ Wl, const float* __restrict__ Wr,
    const float* __restrict__ bl,
    float* __restrict__ P2, float* __restrict__ P1, float* __restrict__ P0,
    float* __restrict__ bias2)
{
    __shared__ MMLds L;
    const int bid = blockIdx.x;
    const int t = threadIdx.x;
    if (bid < 64) { cnt[bid * 256 + t] = 0; return; }
    if (bid == 256) {
        const float* b2 = bl + D;
        const float* b3 = bl + 2 * D;
        const float* L3 = Wl + (size_t)2 * D * D;
        const float* R3 = Wr + (size_t)2 * D * D;
        float s = 0.f;
        #pragma unroll 8
        for (int k = 0; k < D; ++k)
            s += b2[k] * (L3[(size_t)k * D + t] + R3[(size_t)k * D + t]);
        bias2[t] = s + b3[t];
        return;
    }
    int pb = bid - 64;                   // 0..191
    int mat = pb / 64, tile = pb % 64;
    int r0 = (tile >> 3) * 32, c0 = (tile & 7) * 32;
    const float* L2 = Wl + (size_t)1 * D * D;
    const float* R2 = Wr + (size_t)1 * D * D;
    const float* L3 = Wl + (size_t)2 * D * D;
    const float* R3 = Wr + (size_t)2 * D * D;
    float acc[4] = {0.f, 0.f, 0.f, 0.f};
    if (mat == 0) {
        mm32(L2, L3, r0, c0, L, acc);
        mm32_store(P2, r0, c0, acc);
    } else if (mat == 1) {
        mm32(R2, L3, r0, c0, L, acc);
        mm32(L2, R3, r0, c0, L, acc);
        mm32_store(P1, r0, c0, acc);
    } else {
        mm32(R2, R3, r0, c0, L, acc);
        mm32_store(P0, r0, c0, acc);
    }
}

// ---------------------------------------------------------------------------
// Dispatch 2: bucket fill (R14 verbatim)
// ---------------------------------------------------------------------------
__global__ __launch_bounds__(256) void fill_bucket_kernel(const int* __restrict__ edge,
                                                          int* __restrict__ cnt,
                                                          int* __restrict__ col) {
    int e = blockIdx.x * 256 + threadIdx.x;
    int dst = edge[N_EDGES + e];
    int src = edge[e];
    int slot = atomicAdd(&cnt[dst], 1);
    if (slot < MAXDEG) col[dst * MAXDEG + slot] = src;
}

// ---------------------------------------------------------------------------
// Dispatch 3: aggx (R14 verbatim): A[i] = mean_{j in in(i)} x[j]
// ---------------------------------------------------------------------------
__global__ __launch_bounds__(256) void aggx_kernel(const float* __restrict__ x,
                                                   const int* __restrict__ cnt,
                                                   const int* __restrict__ col,
                                                   float* __restrict__ A) {
    int node = blockIdx.x * 4 + (threadIdx.x >> 6);
    int lane = threadIdx.x & 63;
    int c = cnt[node];
    if (c > MAXDEG) c = MAXDEG;
    int my = (lane < c) ? col[node * MAXDEG + lane] : 0;
    float a0 = 0.f, a1 = 0.f, a2 = 0.f, a3 = 0.f;
    int j = 0;
    for (; j + 8 <= c; j += 8) {
        float4 v[8];
        #pragma unroll
        for (int q = 0; q < 8; ++q) {
            int s = __shfl(my, j + q);
            v[q] = *(const float4*)&x[(size_t)s * D + lane * 4];
        }
        #pragma unroll
        for (int q = 0; q < 8; ++q) {
            a0 += v[q].x; a1 += v[q].y; a2 += v[q].z; a3 += v[q].w;
        }
    }
    for (; j < c; ++j) {
        int s = __shfl(my, j);
        float4 v = *(const float4*)&x[(size_t)s * D + lane * 4];
        a0 += v.x; a1 += v.y; a2 += v.z; a3 += v.w;
    }
    float id = 1.0f / (float)(c < 1 ? 1 : c);
    float4 r = make_float4(a0 * id, a1 * id, a2 * id, a3 * id);
    *(float4*)&A[(size_t)node * D + lane * 4] = r;
}

// ---------------------------------------------------------------------------
// Dispatch 4: telescoped tail — R14 gather + layer-1 + head VERBATIM;
// layers 2+3 replaced by ONE folded phase (P fold, algebra == R19's P):
//   v0=g1@Wl1+g0@Wr1+b1 ; v1=g2@Wl1+g1@Wr1+b1 ; v2=g3@Wl1+g2@Wr1+b1
//   X3 = v2@P2 + v1@P1 + v0@P0 + bias2 ; out = MLP head(X3)
// ---------------------------------------------------------------------------
__global__ __launch_bounds__(1024) void tail_kernel(
    const int* __restrict__ cnt, const int* __restrict__ col,
    const float* __restrict__ x, const float* __restrict__ A,
    const float* __restrict__ Wl, const float* __restrict__ bl,
    const float* __restrict__ Wr,
    const float* __restrict__ P2, const float* __restrict__ P1,
    const float* __restrict__ P0, const float* __restrict__ bias2,
    const float* __restrict__ Wh, const float* __restrict__ bh,
    const float* __restrict__ Wo, const float* __restrict__ bo,
    float* __restrict__ out)
{
    __shared__ float g0[D], g1[D], g2[D], g3[D];
    __shared__ float v0[D], v1[D], v2[D];
    __shared__ float part1[16][D];
    __shared__ float part2[16][D];
    __shared__ int nbr[MAXDEG];
    __shared__ int snr;

    const int b = blockIdx.x, t = threadIdx.x;
    const int w = t >> 6, lane = t & 63;
    const int root = b * NODES_PER_GRAPH;

    if (t == 0) { int cc = cnt[root]; snr = (cc > MAXDEG) ? MAXDEG : cc; }
    __syncthreads();
    const int c0 = snr;
    if (t < c0) nbr[t] = col[root * MAXDEG + t];
    if (t < D) {
        g0[t] = x[(size_t)root * D + t];
        g1[t] = A[(size_t)root * D + t];
    }
    __syncthreads();

    // ---- 1/2-hop gathers of A (R14-proven, verbatim) ----
    {
        float p1[4] = {0.f, 0.f, 0.f, 0.f}, p2[4] = {0.f, 0.f, 0.f, 0.f};
        for (int i = w; i < c0; i += 16) {
            int n = nbr[i];
            {
                float4 v = *(const float4*)&A[(size_t)n * D + lane * 4];
                p1[0] += v.x; p1[1] += v.y; p1[2] += v.z; p1[3] += v.w;
            }
            int c = cnt[n]; if (c > MAXDEG) c = MAXDEG;
            int my = (lane < c) ? col[n * MAXDEG + lane] : 0;
            float a[4] = {0.f, 0.f, 0.f, 0.f};
            int j = 0;
            for (; j + 4 <= c; j += 4) {
                float4 v[4];
                #pragma unroll
                for (int q = 0; q < 4; ++q) {
                    int s = __shfl(my, j + q);
                    v[q] = *(const float4*)&A[(size_t)s * D + lane * 4];
                }
                #pragma unroll
                for (int q = 0; q < 4; ++q) {
                    a[0] += v[q].x; a[1] += v[q].y; a[2] += v[q].z; a[3] += v[q].w;
                }
            }
            for (; j < c; ++j) {
                int s = __shfl(my, j);
                float4 v = *(const float4*)&A[(size_t)s * D + lane * 4];
                a[0] += v.x; a[1] += v.y; a[2] += v.z; a[3] += v.w;
            }
            float id = 1.0f / (float)(c < 1 ? 1 : c);
            #pragma unroll
            for (int q = 0; q < 4; ++q) p2[q] += a[q] * id;
        }
        #pragma unroll
        for (int q = 0; q < 4; ++q) {
            part1[w][lane * 4 + q] = p1[q];
            part2[w][lane * 4 + q] = p2[q];
        }
        __syncthreads();
        if (t < D) {
            float s1 = 0.f, s2 = 0.f;
            #pragma unroll
            for (int ww = 0; ww < 16; ++ww) { s1 += part1[ww][t]; s2 += part2[ww][t]; }
            float id0 = 1.0f / (float)(c0 < 1 ? 1 : c0);
            g2[t] = s1 * id0;
            g3[t] = s2 * id0;
        }
        __syncthreads();
    }

    const int c = t & 255, kq = t >> 8;
    // ---- layer 1: v0,v1,v2 in one pass over Wl1/Wr1 (R14-proven idiom) ----
    {
        const float* WL = Wl;
        const float* WR = Wr;
        float a0 = 0.f, a1 = 0.f, a2 = 0.f;
        #pragma unroll 8
        for (int k0 = 0; k0 < 64; ++k0) {
            int k = kq * 64 + k0;
            float wl = WL[(size_t)k * D + c];
            float wr = WR[(size_t)k * D + c];
            a0 += g1[k] * wl + g0[k] * wr;
            a1 += g2[k] * wl + g1[k] * wr;
            a2 += g3[k] * wl + g2[k] * wr;
        }
        part1[kq][c] = a0; part1[4 + kq][c] = a1; part1[8 + kq][c] = a2;
        __syncthreads();
        if (t < D) {
            float s0 = 0.f, s1 = 0.f, s2 = 0.f;
            #pragma unroll
            for (int i = 0; i < 4; ++i) {
                s0 += part1[i][t]; s1 += part1[4 + i][t]; s2 += part1[8 + i][t];
            }
            float bb = bl[t];
            v0[t] = s0 + bb; v1[t] = s1 + bb; v2[t] = s2 + bb;
        }
        __syncthreads();
    }
    // ---- folded layers 2+3: X3 = v2@P2 + v1@P1 + v0@P0 + bias2 ----
    {
        float a = 0.f;
        #pragma unroll 8
        for (int k0 = 0; k0 < 64; ++k0) {
            int k = kq * 64 + k0;
            a += v2[k] * P2[(size_t)k * D + c]
               + v1[k] * P1[(size_t)k * D + c]
               + v0[k] * P0[(size_t)k * D + c];
        }
        part1[kq][c] = a;
        __syncthreads();
        if (t < D) {
            float s = part1[0][t] + part1[1][t] + part1[2][t] + part1[3][t];
            v0[t] = s + bias2[t];
        }
        __syncthreads();
    }
    // ---- MLP head (R14-proven, verbatim) ----
    for (int l = 0; l < 3; ++l) {
        const float* W = (l < 2) ? Wh + (size_t)l * D * D : Wo;
        float a = 0.f;
        #pragma unroll
        for (int k0 = 0; k0 < 64; k0 += 8) {
            float wv[8];
            #pragma unroll
            for (int j = 0; j < 8; ++j)
                wv[j] = W[(size_t)(kq * 64 + k0 + j) * D + c];
            #pragma unroll
            for (int j = 0; j < 8; ++j)
                a += v0[kq * 64 + k0 + j] * wv[j];
        }
        part1[kq][c] = a;
        __syncthreads();
        if (t < D) {
            float v = part1[0][t] + part1[1][t] + part1[2][t] + part1[3][t]
                    + ((l < 2) ? bh[(size_t)l * D + t] : bo[t]);
            if (l < 2) v0[t] = fmaxf(v, 0.f);
            else       out[(size_t)b * D + t] = v;
        }
        __syncthreads();
    }
}

// ---------------------------------------------------------------------------
extern "C" void kernel_launch(void* const* d_in, const int* in_sizes, int n_in,
                              void* d_out, int out_size, void* d_ws, size_t ws_size,
                              hipStream_t stream) {
    const float* x    = (const float*)d_in[0];
    const int*   edge = (const int*)d_in[1];
    const float* Wl   = (const float*)d_in[2];
    const float* bl   = (const float*)d_in[3];
    const float* Wr   = (const float*)d_in[4];
    const float* Wh   = (const float*)d_in[5];
    const float* bh   = (const float*)d_in[6];
    const float* Wo   = (const float*)d_in[7];
    const float* bo   = (const float*)d_in[8];
    float* out = (float*)d_out;

    char* w = (char*)d_ws;
    auto alloc = [&](size_t bytes) {
        char* p = w;
        w += (bytes + 255) & ~(size_t)255;
        return p;
    };
    int*   cnt   = (int*)  alloc((size_t)N_NODES * 4);
    int*   col   = (int*)  alloc((size_t)N_NODES * MAXDEG * 4);
    float* A     = (float*)alloc((size_t)N_NODES * D * 4);
    float* P2    = (float*)alloc((size_t)D * D * 4);
    float* P1    = (float*)alloc((size_t)D * D * 4);
    float* P0    = (float*)alloc((size_t)D * D * 4);
    float* bias2 = (float*)alloc((size_t)D * 4);

    init_p_kernel<<<257, 256, 0, stream>>>(cnt, Wl, Wr, bl, P2, P1, P0, bias2);
    fill_bucket_kernel<<<N_EDGES / 256, 256, 0, stream>>>(edge, cnt, col);
    aggx_kernel<<<N_NODES / 4, 256, 0, stream>>>(x, cnt, col, A);
    tail_kernel<<<B_GRAPHS, 1024, 0, stream>>>(cnt, col, x, A,
                                               Wl, bl, Wr,
                                               P2, P1, P0, bias2,
                                               Wh, bh, Wo, bo, out);
}

// Round 22
// 79.178 us; speedup vs baseline: 1.7737x; 1.4150x over previous
//
#include <hip/hip_runtime.h>

#define N_NODES 16384
#define N_EDGES 262144
#define D 256
#define B_GRAPHS 32
#define NODES_PER_GRAPH 512   // N_NODES / B_GRAPHS
#define MAXDEG 64             // Poisson(16): P(deg>64) ~ 1e-17

typedef unsigned short u16;
typedef __attribute__((ext_vector_type(4))) unsigned short u16x4;
typedef __attribute__((ext_vector_type(8))) unsigned short u16x8;

static __device__ __forceinline__ u16 f2bf(float f) {
    unsigned int u = __float_as_uint(f);
    unsigned int r = (u + 0x7FFFu + ((u >> 16) & 1u)) >> 16;   // RNE
    return (u16)r;
}
static __device__ __forceinline__ float bf2f(u16 h) {
    return __uint_as_float(((unsigned int)h) << 16);
}

// weight-bf16 layout offsets (u16 elements) in wbf:
//  Wl: 0          (3*65536)
//  Wr: 196608     (3*65536)
//  Wh: 393216     (2*65536)
//  Wo: 524288     (65536)
#define WOFF_WL 0
#define WOFF_WR 196608
#define WOFF_WH 393216
#define WOFF_WO 524288
#define WTOTAL  589824

// ---------------------------------------------------------------------------
// Dispatch 1: bid<64 zero cnt; [64,2112) x->bf16; [2112,2400) weights->bf16
// ---------------------------------------------------------------------------
__global__ __launch_bounds__(256) void prep_kernel(
    const float* __restrict__ x,
    const float* __restrict__ Wl, const float* __restrict__ Wr,
    const float* __restrict__ Wh, const float* __restrict__ Wo,
    int* __restrict__ cnt, u16* __restrict__ xb, u16* __restrict__ wbf)
{
    const int bid = blockIdx.x;
    const int t = threadIdx.x;
    if (bid < 64) { cnt[bid * 256 + t] = 0; return; }
    if (bid < 2112) {
        size_t e0 = ((size_t)(bid - 64) * 256 + t) * 8;
        float4 v0 = *(const float4*)&x[e0];
        float4 v1 = *(const float4*)&x[e0 + 4];
        float xs[8] = {v0.x, v0.y, v0.z, v0.w, v1.x, v1.y, v1.z, v1.w};
        u16x8 H;
        #pragma unroll
        for (int j = 0; j < 8; ++j) H[j] = f2bf(xs[j]);
        *(u16x8*)&xb[e0] = H;
        return;
    }
    size_t off = ((size_t)(bid - 2112) * 256 + t) * 8;
    const float* src; size_t so = off;
    if (off < WOFF_WR)      { src = Wl; }
    else if (off < WOFF_WH) { src = Wr; so -= WOFF_WR; }
    else if (off < WOFF_WO) { src = Wh; so -= WOFF_WH; }
    else                    { src = Wo; so -= WOFF_WO; }
    float4 v0 = *(const float4*)&src[so];
    float4 v1 = *(const float4*)&src[so + 4];
    float xs[8] = {v0.x, v0.y, v0.z, v0.w, v1.x, v1.y, v1.z, v1.w};
    u16x8 H;
    #pragma unroll
    for (int j = 0; j < 8; ++j) H[j] = f2bf(xs[j]);
    *(u16x8*)&wbf[off] = H;
}

// ---------------------------------------------------------------------------
// Dispatch 2: bucket fill (R14 verbatim)
// ---------------------------------------------------------------------------
__global__ __launch_bounds__(256) void fill_bucket_kernel(const int* __restrict__ edge,
                                                          int* __restrict__ cnt,
                                                          int* __restrict__ col) {
    int e = blockIdx.x * 256 + threadIdx.x;
    int dst = edge[N_EDGES + e];
    int src = edge[e];
    int slot = atomicAdd(&cnt[dst], 1);
    if (slot < MAXDEG) col[dst * MAXDEG + slot] = src;
}

// ---------------------------------------------------------------------------
// Dispatch 3: aggx on bf16 x (R6-proven gather idiom), A stored bf16.
// ---------------------------------------------------------------------------
__global__ __launch_bounds__(256) void aggx_kernel(const u16* __restrict__ xb,
                                                   const int* __restrict__ cnt,
                                                   const int* __restrict__ col,
                                                   u16* __restrict__ Ab) {
    int node = blockIdx.x * 4 + (threadIdx.x >> 6);
    int lane = threadIdx.x & 63;
    int c = cnt[node];
    if (c > MAXDEG) c = MAXDEG;
    int my = (lane < c) ? col[node * MAXDEG + lane] : 0;
    float a0 = 0.f, a1 = 0.f, a2 = 0.f, a3 = 0.f;
    int j = 0;
    for (; j + 8 <= c; j += 8) {
        u16x4 v[8];
        #pragma unroll
        for (int q = 0; q < 8; ++q) {
            int s = __shfl(my, j + q);
            v[q] = *(const u16x4*)&xb[(size_t)s * D + lane * 4];
        }
        #pragma unroll
        for (int q = 0; q < 8; ++q) {
            a0 += bf2f(v[q][0]); a1 += bf2f(v[q][1]);
            a2 += bf2f(v[q][2]); a3 += bf2f(v[q][3]);
        }
    }
    for (; j < c; ++j) {
        int s = __shfl(my, j);
        u16x4 v = *(const u16x4*)&xb[(size_t)s * D + lane * 4];
        a0 += bf2f(v[0]); a1 += bf2f(v[1]); a2 += bf2f(v[2]); a3 += bf2f(v[3]);
    }
    float id = 1.0f / (float)(c < 1 ? 1 : c);
    float m[4] = {a0 * id, a1 * id, a2 * id, a3 * id};
    u16x4 H;
    #pragma unroll
    for (int q = 0; q < 4; ++q) H[q] = f2bf(m[q]);
    *(u16x4*)&Ab[(size_t)node * D + lane * 4] = H;
}

// ---------------------------------------------------------------------------
// Dispatch 4: telescoped tail — R14 structure VERBATIM (gather, layer1 with
// v0/v1/v2, layer2, layer3, 3-layer head); only storage types changed:
// A gathers read bf16, all 9 weight matrices read bf16 (f32 accumulate).
// ---------------------------------------------------------------------------
__global__ __launch_bounds__(1024) void tail_kernel(
    const int* __restrict__ cnt, const int* __restrict__ col,
    const float* __restrict__ x, const u16* __restrict__ Ab,
    const u16* __restrict__ wbf, const float* __restrict__ bl,
    const float* __restrict__ bh, const float* __restrict__ bo,
    float* __restrict__ out)
{
    __shared__ float g0[D], g1[D], g2[D], g3[D];
    __shared__ float v0[D], v1[D], v2[D], hA[D], hB[D];
    __shared__ float part1[16][D];
    __shared__ float part2[16][D];
    __shared__ int nbr[MAXDEG];
    __shared__ int snr;

    const int b = blockIdx.x, t = threadIdx.x;
    const int w = t >> 6, lane = t & 63;
    const int root = b * NODES_PER_GRAPH;

    if (t == 0) { int cc = cnt[root]; snr = (cc > MAXDEG) ? MAXDEG : cc; }
    __syncthreads();
    const int c0 = snr;
    if (t < c0) nbr[t] = col[root * MAXDEG + t];
    if (t < D) {
        g0[t] = x[(size_t)root * D + t];             // root row: full f32
        g1[t] = bf2f(Ab[(size_t)root * D + t]);
    }
    __syncthreads();

    // ---- 1/2-hop gathers of A (R14 loop structure; bf16 reads) ----
    {
        float p1[4] = {0.f, 0.f, 0.f, 0.f}, p2[4] = {0.f, 0.f, 0.f, 0.f};
        for (int i = w; i < c0; i += 16) {
            int n = nbr[i];
            {
                u16x4 v = *(const u16x4*)&Ab[(size_t)n * D + lane * 4];
                p1[0] += bf2f(v[0]); p1[1] += bf2f(v[1]);
                p1[2] += bf2f(v[2]); p1[3] += bf2f(v[3]);
            }
            int c = cnt[n]; if (c > MAXDEG) c = MAXDEG;
            int my = (lane < c) ? col[n * MAXDEG + lane] : 0;
            float a[4] = {0.f, 0.f, 0.f, 0.f};
            int j = 0;
            for (; j + 4 <= c; j += 4) {
                u16x4 v[4];
                #pragma unroll
                for (int q = 0; q < 4; ++q) {
                    int s = __shfl(my, j + q);
                    v[q] = *(const u16x4*)&Ab[(size_t)s * D + lane * 4];
                }
                #pragma unroll
                for (int q = 0; q < 4; ++q) {
                    a[0] += bf2f(v[q][0]); a[1] += bf2f(v[q][1]);
                    a[2] += bf2f(v[q][2]); a[3] += bf2f(v[q][3]);
                }
            }
            for (; j < c; ++j) {
                int s = __shfl(my, j);
                u16x4 v = *(const u16x4*)&Ab[(size_t)s * D + lane * 4];
                a[0] += bf2f(v[0]); a[1] += bf2f(v[1]);
                a[2] += bf2f(v[2]); a[3] += bf2f(v[3]);
            }
            float id = 1.0f / (float)(c < 1 ? 1 : c);
            #pragma unroll
            for (int q = 0; q < 4; ++q) p2[q] += a[q] * id;
        }
        #pragma unroll
        for (int q = 0; q < 4; ++q) {
            part1[w][lane * 4 + q] = p1[q];
            part2[w][lane * 4 + q] = p2[q];
        }
        __syncthreads();
        if (t < D) {
            float s1 = 0.f, s2 = 0.f;
            #pragma unroll
            for (int ww = 0; ww < 16; ++ww) { s1 += part1[ww][t]; s2 += part2[ww][t]; }
            float id0 = 1.0f / (float)(c0 < 1 ? 1 : c0);
            g2[t] = s1 * id0;
            g3[t] = s2 * id0;
        }
        __syncthreads();
    }

    const int c = t & 255, kq = t >> 8;
    // ---- layer 1: v0,v1,v2 in one pass over Wl1/Wr1 (bf16 weights) ----
    {
        const u16* WL = wbf + WOFF_WL;
        const u16* WR = wbf + WOFF_WR;
        float a0 = 0.f, a1 = 0.f, a2 = 0.f;
        #pragma unroll 8
        for (int k0 = 0; k0 < 64; ++k0) {
            int k = kq * 64 + k0;
            float wl = bf2f(WL[(size_t)k * D + c]);
            float wr = bf2f(WR[(size_t)k * D + c]);
            a0 += g1[k] * wl + g0[k] * wr;
            a1 += g2[k] * wl + g1[k] * wr;
            a2 += g3[k] * wl + g2[k] * wr;
        }
        part1[kq][c] = a0; part1[4 + kq][c] = a1; part1[8 + kq][c] = a2;
        __syncthreads();
        if (t < D) {
            float s0 = 0.f, s1 = 0.f, s2 = 0.f;
            #pragma unroll
            for (int i = 0; i < 4; ++i) {
                s0 += part1[i][t]; s1 += part1[4 + i][t]; s2 += part1[8 + i][t];
            }
            float bb = bl[t];
            v0[t] = s0 + bb; v1[t] = s1 + bb; v2[t] = s2 + bb;
        }
        __syncthreads();
    }
    // ---- layer 2: hA = v2@Wl2 + v1@Wr2 + b2 ; hB = v1@Wl2 + v0@Wr2 + b2 ----
    {
        const u16* WL = wbf + WOFF_WL + (size_t)1 * D * D;
        const u16* WR = wbf + WOFF_WR + (size_t)1 * D * D;
        float aA = 0.f, aB = 0.f;
        #pragma unroll 8
        for (int k0 = 0; k0 < 64; ++k0) {
            int k = kq * 64 + k0;
            float wl = bf2f(WL[(size_t)k * D + c]);
            float wr = bf2f(WR[(size_t)k * D + c]);
            float h2 = v2[k], h1 = v1[k], h0 = v0[k];
            aA += h2 * wl + h1 * wr;
            aB += h1 * wl + h0 * wr;
        }
        part1[kq][c] = aA; part1[4 + kq][c] = aB;
        __syncthreads();
        if (t < D) {
            float sA = 0.f, sB = 0.f;
            #pragma unroll
            for (int i = 0; i < 4; ++i) { sA += part1[i][t]; sB += part1[4 + i][t]; }
            float bb = bl[D + t];
            hA[t] = sA + bb; hB[t] = sB + bb;
        }
        __syncthreads();
    }
    // ---- layer 3: v0 <- hA@Wl3 + hB@Wr3 + b3 (head input) ----
    {
        const u16* WL = wbf + WOFF_WL + (size_t)2 * D * D;
        const u16* WR = wbf + WOFF_WR + (size_t)2 * D * D;
        float a = 0.f;
        #pragma unroll 8
        for (int k0 = 0; k0 < 64; ++k0) {
            int k = kq * 64 + k0;
            a += hA[k] * bf2f(WL[(size_t)k * D + c])
               + hB[k] * bf2f(WR[(size_t)k * D + c]);
        }
        part1[kq][c] = a;
        __syncthreads();
        if (t < D) {
            float s = part1[0][t] + part1[1][t] + part1[2][t] + part1[3][t];
            v0[t] = s + bl[2 * D + t];
        }
        __syncthreads();
    }
    // ---- MLP head (R14-proven idiom; bf16 weights) ----
    for (int l = 0; l < 3; ++l) {
        const u16* W = (l < 2) ? (wbf + WOFF_WH + (size_t)l * D * D)
                               : (wbf + WOFF_WO);
        float a = 0.f;
        #pragma unroll
        for (int k0 = 0; k0 < 64; k0 += 8) {
            float wv[8];
            #pragma unroll
            for (int j = 0; j < 8; ++j)
                wv[j] = bf2f(W[(size_t)(kq * 64 + k0 + j) * D + c]);
            #pragma unroll
            for (int j = 0; j < 8; ++j)
                a += v0[kq * 64 + k0 + j] * wv[j];
        }
        part1[kq][c] = a;
        __syncthreads();
        if (t < D) {
            float v = part1[0][t] + part1[1][t] + part1[2][t] + part1[3][t]
                    + ((l < 2) ? bh[(size_t)l * D + t] : bo[t]);
            if (l < 2) v0[t] = fmaxf(v, 0.f);
            else       out[(size_t)b * D + t] = v;
        }
        __syncthreads();
    }
}

// ---------------------------------------------------------------------------
extern "C" void kernel_launch(void* const* d_in, const int* in_sizes, int n_in,
                              void* d_out, int out_size, void* d_ws, size_t ws_size,
                              hipStream_t stream) {
    const float* x    = (const float*)d_in[0];
    const int*   edge = (const int*)d_in[1];
    const float* Wl   = (const float*)d_in[2];
    const float* bl   = (const float*)d_in[3];
    const float* Wr   = (const float*)d_in[4];
    const float* Wh   = (const float*)d_in[5];
    const float* bh   = (const float*)d_in[6];
    const float* Wo   = (const float*)d_in[7];
    const float* bo   = (const float*)d_in[8];
    float* out = (float*)d_out;

    char* w = (char*)d_ws;
    auto alloc = [&](size_t bytes) {
        char* p = w;
        w += (bytes + 255) & ~(size_t)255;
        return p;
    };
    int* cnt = (int*)alloc((size_t)N_NODES * 4);
    int* col = (int*)alloc((size_t)N_NODES * MAXDEG * 4);
    u16* xb  = (u16*)alloc((size_t)N_NODES * D * 2);
    u16* Ab  = (u16*)alloc((size_t)N_NODES * D * 2);
    u16* wbf = (u16*)alloc((size_t)WTOTAL * 2);

    prep_kernel<<<2400, 256, 0, stream>>>(x, Wl, Wr, Wh, Wo, cnt, xb, wbf);
    fill_bucket_kernel<<<N_EDGES / 256, 256, 0, stream>>>(edge, cnt, col);
    aggx_kernel<<<N_NODES / 4, 256, 0, stream>>>(xb, cnt, col, Ab);
    tail_kernel<<<B_GRAPHS, 1024, 0, stream>>>(cnt, col, x, Ab, wbf,
                                               bl, bh, bo, out);
}